// Round 1
// baseline (376.902 us; speedup 1.0000x reference)
//
#include <hip/hip_runtime.h>
#include <hip/hip_bf16.h>
#include <stdint.h>

typedef _Float16 f16;
typedef _Float16 f16x8 __attribute__((ext_vector_type(8)));
typedef float f32x16 __attribute__((ext_vector_type(16)));
typedef float f32x4 __attribute__((ext_vector_type(4)));
typedef uint32_t u32x4 __attribute__((ext_vector_type(4)));
typedef uint32_t u32x2 __attribute__((ext_vector_type(2)));

#define MFMA(A, B, C) __builtin_amdgcn_mfma_f32_32x32x16_f16((A), (B), (C), 0, 0, 0)

// ---------------------------------------------------------------------------
// Kernel 1: x NCHW f32 [32,256,64,64] -> xt2 f16, MFMA-native layout:
//   16B unit U = ((((b*64+h)*8 + c32)*4 + g)*2 + (w&1))*32 + (w>>1)
//   (c = c32*32 + g*8 + e). A-fragment loads become contiguous 512B runs.
// (unchanged, correctness-proven)
// ---------------------------------------------------------------------------
__global__ __launch_bounds__(256) void nchw_to_nhwc_f16(
    const float* __restrict__ x, f16* __restrict__ xt) {
  __shared__ __align__(16) uint32_t tile[64 * 128];  // 32768 B
  const int bh = blockIdx.x;  // b*64 + h
  const int t = threadIdx.x;
  const float* src = x + (size_t)(bh >> 6) * (256 * 4096) + (bh & 63) * 64;

  const int w4 = t & 15;            // float4 index along w
  const int cq = t >> 4;            // c-quad 0..15
  const int xorv = 4 * (w4 & 7);    // = 4*((w>>2)&7) since w = w4*4+jw
#pragma unroll
  for (int it = 0; it < 4; ++it) {
    const int c0 = it * 64 + cq * 4;
    float4 v0 = *(const float4*)(src + (size_t)(c0 + 0) * 4096 + w4 * 4);
    float4 v1 = *(const float4*)(src + (size_t)(c0 + 1) * 4096 + w4 * 4);
    float4 v2 = *(const float4*)(src + (size_t)(c0 + 2) * 4096 + w4 * 4);
    float4 v3 = *(const float4*)(src + (size_t)(c0 + 3) * 4096 + w4 * 4);
    const float* p0 = (const float*)&v0;
    const float* p1 = (const float*)&v1;
    const float* p2 = (const float*)&v2;
    const float* p3 = (const float*)&v3;
    const int u = it * 32 + cq * 2;  // even word index (c-pair)
#pragma unroll
    for (int jw = 0; jw < 4; ++jw) {
      f16 h0 = (f16)p0[jw], h1 = (f16)p1[jw], h2 = (f16)p2[jw], h3 = (f16)p3[jw];
      uint32_t lo = (uint32_t)__builtin_bit_cast(uint16_t, h0) |
                    ((uint32_t)__builtin_bit_cast(uint16_t, h1) << 16);
      uint32_t hi = (uint32_t)__builtin_bit_cast(uint16_t, h2) |
                    ((uint32_t)__builtin_bit_cast(uint16_t, h3) << 16);
      u32x2 pk = {lo, hi};
      const int w = w4 * 4 + jw;
      *(u32x2*)&tile[w * 128 + (u ^ xorv)] = pk;
    }
  }
  __syncthreads();
  f16* dstb = xt + (size_t)bh * 16384;
#pragma unroll
  for (int it = 0; it < 8; ++it) {
    const int n = it * 256 + t;       // local 16B-unit index, 0..2047
    const int w2 = n & 31;
    const int par = (n >> 5) & 1;
    const int g8 = n >> 6;            // c-octet 0..31
    const int w = par + 2 * w2;
    const u32x4 v = *(const u32x4*)&tile[w * 128 + ((g8 * 4) ^ (4 * ((w >> 2) & 7)))];
    *(u32x4*)(dstb + n * 8) = v;
  }
}

// ---------------------------------------------------------------------------
// Kernel 2: W [32co][256ci][9][9] f32 -> wt2 f16:
//   byte = (((kk*8 + cic)*4 + sg)*32 + co)*16 + e*2,  ci = cic*32 + s*16+hh*8+e,
//   sg = s*2+hh. B-fragment loads become two contiguous 512B runs.
// (unchanged)
// ---------------------------------------------------------------------------
__global__ __launch_bounds__(256) void pack_w(const float* __restrict__ W,
                                              f16* __restrict__ wt) {
  __shared__ float lds[10368];  // [128 ci][81 kk]
  const int t = threadIdx.x;
  const int co = blockIdx.x >> 1;
  const int cih = blockIdx.x & 1;
  const float* src = W + (size_t)(co * 256 + cih * 128) * 81;
  for (int i = t; i < 10368; i += 256) lds[i] = src[i];
  __syncthreads();
  for (int j = t; j < 1296; j += 256) {
    const int kk = j >> 4;
    const int t16 = j & 15;
    const int cicl = t16 >> 2;       // cic within half, 0..3
    const int sg = t16 & 3;          // s*2 + hh
    const int cin = ((sg >> 1) & 1) * 16 + (sg & 1) * 8;  // ci offset in 32
    f16 tmp[8];
#pragma unroll
    for (int e = 0; e < 8; ++e)
      tmp[e] = (f16)lds[(cicl * 32 + cin + e) * 81 + kk];
    const int cic = cih * 4 + cicl;
    *(f16x8*)&wt[(size_t)(((kk * 8 + cic) * 4 + sg) * 32 + co) * 8] = *(f16x8*)tmp;
  }
}

// ---------------------------------------------------------------------------
// Kernel 3: direct conv, mfma_f32_32x32x16_f16, oh-PAIRED (M=64 via 2 acc).
// 896 blocks = 32 b x 14 ohp x 2 cih; 4 waves (cic = cih*4+wave).
//
// r0 change: B-weights now flow through LDS (global_load_lds width=16,
// 2 x 16KB double buffer, one __syncthreads per (slab,kw) step). Rationale:
// B fragments are a zero-reuse 1KB/MFMA stream that thrashed L1 (144KB/slab
// per block >> 32KB) and pinned feed BW at the per-CU L2 share (~40B/cyc vs
// 192B/cyc demand -> 19% MfmaUtil). LDS adds a dedicated ~128B/cyc B port
// and un-thrashes L1 so A's in-slab re-reads hit L1. A uses a depth-1
// register prefetch, continuous across slab boundaries (no per-slab restart).
// LDS stage buffers alias the 16.9KB reduction scratch: 32KB total,
// 5 blocks/CU by LDS (grid gives 3.5).
// ---------------------------------------------------------------------------
__global__ __launch_bounds__(256, 3) void conv_direct(
    const f16* __restrict__ xt, const f16* __restrict__ wt,
    float* __restrict__ convp) {
  __shared__ __align__(16) char smem[32768];  // 2x16KB B-stage, aliased w/ red
  const int tid = threadIdx.x;
  const int lane = tid & 63;
  const int wave = tid >> 6;
  const int m = lane & 31;
  const int hh = lane >> 5;

  const int blk = blockIdx.x;
  const int xcd = blk & 7;
  const int r = blk >> 3;             // 0..111
  const int i4 = r / 28;              // 0..3
  const int rr = r - i4 * 28;
  const int bimg = xcd * 4 + i4;      // image on one XCD (L2 affinity)
  const int ohp = rr >> 1;            // 0..13
  const int cih = rr & 1;
  const int cic = cih * 4 + wave;     // this wave's 32-ci chunk (c32)

  const char* xb = (const char*)xt;
  const char* wb = (const char*)wt;

  // A lane base for slab j=0: byte = (bimg*64 + 4ohp)*32768 + cic*4096
  //                                  + hh*1024 + m*16 ; per slab += 32768.
  const char* ab = xb + ((size_t)(bimg * 64 + 4 * ohp) * 32768 +
                         cic * 4096 + hh * 1024 + m * 16);
  const size_t cih8192 = (size_t)cih * 8192;
  const int t16 = tid * 16;
  char* stg = smem;
  // Wave's fragment offset inside a staged 8KB chunk (linear copy of global):
  //   (cic - cih*4)*2048 + s*1024 + hh*512 + m*16  (s via +1024 immediates)
  const int fragoff = wave * 2048 + hh * 512 + m * 16;

#define GLDS(G, L)                                                            \
  __builtin_amdgcn_global_load_lds(                                           \
      (const __attribute__((address_space(1))) void*)(G),                     \
      (__attribute__((address_space(3))) void*)(L), 16, 0, 0)

#define ALOAD(AB, KW, P) \
  (*(const f16x8*)((AB) + (P)*2048 + ((KW)&1) * 512 + ((KW) >> 1) * 16))

  // Stage 16KB: T0 chunk (kk=KKA, this cih half, 8KB contiguous) -> +0,
  //             T1 chunk (kk=KKB) -> +8192. 4 x global_load_lds_dwordx4
  // per thread; LDS dest is lane-linear (t*16) as required by HW.
#define STAGE(DST, KKA, KKB)                                                  \
  {                                                                           \
    const char* sA = wb + (size_t)(KKA)*16384 + cih8192 + t16;                \
    const char* sB = wb + (size_t)(KKB)*16384 + cih8192 + t16;                \
    char* d = (DST) + t16;                                                    \
    GLDS(sA, d);                                                              \
    GLDS(sA + 4096, d + 4096);                                                \
    GLDS(sB, d + 8192);                                                       \
    GLDS(sB + 4096, d + 12288);                                               \
  }

  f32x16 acc0, acc1;
#pragma unroll
  for (int i = 0; i < 16; ++i) { acc0[i] = 0.f; acc1[i] = 0.f; }

  // Prologue: stage step (j=0,kw=0) into buf0 (T1 inactive -> junk kk=0);
  // prefetch step-0 A fragments.
  STAGE(stg, 0, 0)
  f16x8 a0n = ALOAD(ab, 0, 0), a1n = ALOAD(ab, 0, 1);
  int p = 0;

  // One step = one (slab,kw): barrier (drains cur stage + A prefetch),
  // issue next stage into buf^1 (hides under this step's compute),
  // issue next A prefetch, consume staged B via ds_read_b128 + 4 MFMA.
#define STEP(T0A, T1A, NKKA, NKKB, ABN, NKW, LAST)                            \
  {                                                                           \
    __syncthreads();                                                          \
    if (!(LAST)) STAGE(stg + (p ^ 1) * 16384, NKKA, NKKB)                     \
    const f16x8 ca0 = a0n, ca1 = a1n;                                         \
    if (!(LAST)) { a0n = ALOAD(ABN, NKW, 0); a1n = ALOAD(ABN, NKW, 1); }      \
    const char* bp = stg + p * 16384 + fragoff;                               \
    if (T0A) {                                                                \
      acc0 = MFMA(ca0, *(const f16x8*)(bp), acc0);                            \
      acc0 = MFMA(ca1, *(const f16x8*)(bp + 1024), acc0);                     \
    }                                                                         \
    if (T1A) {                                                                \
      acc1 = MFMA(ca0, *(const f16x8*)(bp + 8192), acc1);                     \
      acc1 = MFMA(ca1, *(const f16x8*)(bp + 9216), acc1);                     \
    }                                                                         \
    p ^= 1;                                                                   \
  }

  // 9 steps of one slab; crossover params (NSA/NSB = next slab's kk bases,
  // A pointer advances) keep the stage + A pipelines continuous.
#define SLAB9(T0A, T1A, KKA0, KKB0, NSA, NSB, ISLAST)                         \
  {                                                                           \
    _Pragma("unroll") for (int kw = 0; kw < 9; ++kw) {                        \
      const int nkka = kw < 8 ? (KKA0) + kw + 1 : (NSA);                      \
      const int nkkb = kw < 8 ? (KKB0) + kw + 1 : (NSB);                      \
      const char* abn = kw < 8 ? ab : ab + 32768;                             \
      const int nkw = kw < 8 ? kw + 1 : 0;                                    \
      STEP(T0A, T1A, nkka, nkkb, abn, nkw, (ISLAST) && kw == 8)               \
    }                                                                         \
    ab += 32768;                                                              \
  }

  SLAB9(1, 0, 0, 0, 9, 0, 0)                         // j=0 (T0 kh=0)
  SLAB9(1, 0, 9, 0, 18, 0, 0)                        // j=1 (T0 kh=1)
  for (int j = 2; j < 8; ++j) {                      // j=2..7 (both tiles)
    SLAB9(1, 1, j * 9, (j - 2) * 9, (j + 1) * 9, (j - 1) * 9, 0)
  }
  SLAB9(1, 1, 72, 54, 0, 63, 0)                      // j=8
  SLAB9(0, 1, 0, 63, 0, 72, 0)                       // j=9 (T1 kh=7)
  SLAB9(0, 1, 0, 72, 0, 0, 1)                        // j=10 (T1 kh=8), last
#undef SLAB9
#undef STEP
#undef STAGE
#undef ALOAD
#undef GLDS

  // 4-wave reduction, two rounds (T0 -> oh=2ohp, T1 -> oh=2ohp+1).
  // red aliases the stage buffers; the leading __syncthreads ensures all
  // waves are past the main loop before overwrite.
  float* red = (float*)smem;  // 4*32*33*4 = 16896 B <= 32768
  const int mm = tid >> 3;        // 0..31 (ow)
  const int c0 = (tid & 7) * 4;   // 0..28
#pragma unroll
  for (int half = 0; half < 2; ++half) {
    __syncthreads();
#pragma unroll
    for (int rI = 0; rI < 16; ++rI) {
      const int row = (rI & 3) + 8 * (rI >> 2) + 4 * hh;
      red[(wave * 32 + row) * 33 + m] = half ? acc1[rI] : acc0[rI];
    }
    __syncthreads();
    if (mm < 28) {
      float s0 = 0.f, s1 = 0.f, s2 = 0.f, s3 = 0.f;
#pragma unroll
      for (int w = 0; w < 4; ++w) {
        const float* rp = red + (w * 32 + mm) * 33 + c0;
        s0 += rp[0]; s1 += rp[1]; s2 += rp[2]; s3 += rp[3];
      }
      const f32x4 o4 = {s0, s1, s2, s3};
      const int pp = bimg * 784 + (2 * ohp + half) * 28 + mm;
      *(f32x4*)&convp[(size_t)cih * 802816 + (size_t)pp * 32 + c0] = o4;
    }
  }
}

// ---------------------------------------------------------------------------
// Kernel 4: epilogue. v = sum(2 partials)+bias; sq=8v^2;
// scale = sq/((1+sq)*sqrt(sq+1e-8)); y=v*scale broadcast to 8 t-slots.
// (unchanged)
// ---------------------------------------------------------------------------
__global__ __launch_bounds__(256) void epilogue(const float* __restrict__ convp,
                                                const float* __restrict__ bias,
                                                float* __restrict__ out) {
  const int gi = blockIdx.x * 256 + threadIdx.x;  // 100352 total, exact grid
  const int base = gi * 8;
  const int p = gi >> 2;
  const int co0 = (gi & 3) * 8;
  const int bi = p / 784;
  const int pix = p - bi * 784;
  f32x4 v0 = {0.f, 0.f, 0.f, 0.f}, v1 = {0.f, 0.f, 0.f, 0.f};
#pragma unroll
  for (int qq = 0; qq < 2; ++qq) {
    v0 += *(const f32x4*)&convp[(size_t)qq * 802816 + base];
    v1 += *(const f32x4*)&convp[(size_t)qq * 802816 + base + 4];
  }
  float vb[8];
#pragma unroll
  for (int jj = 0; jj < 4; ++jj) {
    vb[jj] = v0[jj] + bias[co0 + jj];
    vb[4 + jj] = v1[jj] + bias[co0 + 4 + jj];
  }
  float* ob = out + (size_t)bi * 200704 + pix * 8;
#pragma unroll
  for (int jj = 0; jj < 8; ++jj) {
    const float vv = vb[jj];
    const float sq = 8.f * vv * vv;
    const float scale = sq / ((1.f + sq) * sqrtf(sq + 1e-8f));
    const float y = vv * scale;
    const f32x4 qv = {y, y, y, y};
    float* o = ob + (size_t)(co0 + jj) * 6272;
    *(f32x4*)o = qv;
    *(f32x4*)(o + 4) = qv;
  }
}

// ---------------------------------------------------------------------------
extern "C" void kernel_launch(void* const* d_in, const int* in_sizes, int n_in,
                              void* d_out, int out_size, void* d_ws,
                              size_t ws_size, hipStream_t stream) {
  const float* x = (const float*)d_in[0];     // [32,256,64,64]
  const float* W = (const float*)d_in[1];     // [32,256,9,9]
  const float* bias = (const float*)d_in[2];  // [32]
  float* out = (float*)d_out;                 // 6422528 f32

  char* ws = (char*)d_ws;
  f16* xt = (f16*)ws;                                // 67,108,864 B
  f16* wt = (f16*)(ws + 67108864);                   //  1,327,104 B
  float* convp = (float*)(ws + 67108864 + 1327104);  //  6,422,528 B (2 halves)

  nchw_to_nhwc_f16<<<dim3(2048), dim3(256), 0, stream>>>(x, xt);
  pack_w<<<dim3(64), dim3(256), 0, stream>>>(W, wt);
  conv_direct<<<dim3(896), dim3(256), 0, stream>>>(xt, wt, convp);
  epilogue<<<dim3(392), dim3(256), 0, stream>>>(convp, bias, out);
}

// Round 2
// 312.597 us; speedup vs baseline: 1.2057x; 1.2057x over previous
//
#include <hip/hip_runtime.h>
#include <hip/hip_bf16.h>
#include <stdint.h>

typedef _Float16 f16;
typedef _Float16 f16x8 __attribute__((ext_vector_type(8)));
typedef float f32x16 __attribute__((ext_vector_type(16)));
typedef float f32x4 __attribute__((ext_vector_type(4)));
typedef uint32_t u32x4 __attribute__((ext_vector_type(4)));
typedef uint32_t u32x2 __attribute__((ext_vector_type(2)));

#define MFMA(A, B, C) __builtin_amdgcn_mfma_f32_32x32x16_f16((A), (B), (C), 0, 0, 0)

// ---------------------------------------------------------------------------
// Kernel 1: x NCHW f32 [32,256,64,64] -> xt2 f16, MFMA-native layout:
//   16B unit U = ((((b*64+h)*8 + c32)*4 + g)*2 + (w&1))*32 + (w>>1)
//   (c = c32*32 + g*8 + e). A-fragment loads become contiguous 512B runs.
// (unchanged, correctness-proven)
// ---------------------------------------------------------------------------
__global__ __launch_bounds__(256) void nchw_to_nhwc_f16(
    const float* __restrict__ x, f16* __restrict__ xt) {
  __shared__ __align__(16) uint32_t tile[64 * 128];  // 32768 B
  const int bh = blockIdx.x;  // b*64 + h
  const int t = threadIdx.x;
  const float* src = x + (size_t)(bh >> 6) * (256 * 4096) + (bh & 63) * 64;

  const int w4 = t & 15;            // float4 index along w
  const int cq = t >> 4;            // c-quad 0..15
  const int xorv = 4 * (w4 & 7);    // = 4*((w>>2)&7) since w = w4*4+jw
#pragma unroll
  for (int it = 0; it < 4; ++it) {
    const int c0 = it * 64 + cq * 4;
    float4 v0 = *(const float4*)(src + (size_t)(c0 + 0) * 4096 + w4 * 4);
    float4 v1 = *(const float4*)(src + (size_t)(c0 + 1) * 4096 + w4 * 4);
    float4 v2 = *(const float4*)(src + (size_t)(c0 + 2) * 4096 + w4 * 4);
    float4 v3 = *(const float4*)(src + (size_t)(c0 + 3) * 4096 + w4 * 4);
    const float* p0 = (const float*)&v0;
    const float* p1 = (const float*)&v1;
    const float* p2 = (const float*)&v2;
    const float* p3 = (const float*)&v3;
    const int u = it * 32 + cq * 2;  // even word index (c-pair)
#pragma unroll
    for (int jw = 0; jw < 4; ++jw) {
      f16 h0 = (f16)p0[jw], h1 = (f16)p1[jw], h2 = (f16)p2[jw], h3 = (f16)p3[jw];
      uint32_t lo = (uint32_t)__builtin_bit_cast(uint16_t, h0) |
                    ((uint32_t)__builtin_bit_cast(uint16_t, h1) << 16);
      uint32_t hi = (uint32_t)__builtin_bit_cast(uint16_t, h2) |
                    ((uint32_t)__builtin_bit_cast(uint16_t, h3) << 16);
      u32x2 pk = {lo, hi};
      const int w = w4 * 4 + jw;
      *(u32x2*)&tile[w * 128 + (u ^ xorv)] = pk;
    }
  }
  __syncthreads();
  f16* dstb = xt + (size_t)bh * 16384;
#pragma unroll
  for (int it = 0; it < 8; ++it) {
    const int n = it * 256 + t;       // local 16B-unit index, 0..2047
    const int w2 = n & 31;
    const int par = (n >> 5) & 1;
    const int g8 = n >> 6;            // c-octet 0..31
    const int w = par + 2 * w2;
    const u32x4 v = *(const u32x4*)&tile[w * 128 + ((g8 * 4) ^ (4 * ((w >> 2) & 7)))];
    *(u32x4*)(dstb + n * 8) = v;
  }
}

// ---------------------------------------------------------------------------
// Kernel 2: W [32co][256ci][9][9] f32 -> wt2 f16:
//   byte = (((kk*8 + cic)*4 + sg)*32 + co)*16 + e*2,  ci = cic*32 + s*16+hh*8+e,
//   sg = s*2+hh. B-fragment loads become two contiguous 512B runs.
// (unchanged)
// ---------------------------------------------------------------------------
__global__ __launch_bounds__(256) void pack_w(const float* __restrict__ W,
                                              f16* __restrict__ wt) {
  __shared__ float lds[10368];  // [128 ci][81 kk]
  const int t = threadIdx.x;
  const int co = blockIdx.x >> 1;
  const int cih = blockIdx.x & 1;
  const float* src = W + (size_t)(co * 256 + cih * 128) * 81;
  for (int i = t; i < 10368; i += 256) lds[i] = src[i];
  __syncthreads();
  for (int j = t; j < 1296; j += 256) {
    const int kk = j >> 4;
    const int t16 = j & 15;
    const int cicl = t16 >> 2;       // cic within half, 0..3
    const int sg = t16 & 3;          // s*2 + hh
    const int cin = ((sg >> 1) & 1) * 16 + (sg & 1) * 8;  // ci offset in 32
    f16 tmp[8];
#pragma unroll
    for (int e = 0; e < 8; ++e)
      tmp[e] = (f16)lds[(cicl * 32 + cin + e) * 81 + kk];
    const int cic = cih * 4 + cicl;
    *(f16x8*)&wt[(size_t)(((kk * 8 + cic) * 4 + sg) * 32 + co) * 8] = *(f16x8*)tmp;
  }
}

// ---------------------------------------------------------------------------
// Kernel 3: direct conv, mfma_f32_32x32x16_f16 — kk-MAJOR, WEIGHT-SHARED.
// r1 redesign: each wave owns FOUR oh tiles (acc x4). For fixed (kh,kw) the
// wave loads B once (2 KB) and applies it to 4 A rows (h = 8og+kh+2t) ->
// B bytes/MFMA drop 4x (the L2-resident B stream was 2/3 of r(-1)'s feed
// bytes). kh walks in same-parity chains (0,2,4,6,8 / 1,3,5,7): consecutive
// steps share 3 of 4 A rows -> A shift register reuses 6/8 frags per step.
// Per wave: 432 loads / 648 MFMAs = 0.67 KB/MFMA (r-1: 1.61). No LDS, no
// barriers in the hot loop: all loads compiler-tracked VGPR loads (the
// r(-1)-proven scheduling regime; r0's per-step barrier drain is reverted).
// Grid 448 = 8 xcd x 4 img x 7 og x 2 cih; 4 waves = 4 cic of the cih half.
// ---------------------------------------------------------------------------
__global__ __launch_bounds__(256, 2) void conv_direct(
    const f16* __restrict__ xt, const f16* __restrict__ wt,
    float* __restrict__ convp) {
  __shared__ float red[4 * 32 * 33];  // 16896 B
  const int tid = threadIdx.x;
  const int lane = tid & 63;
  const int wave = tid >> 6;
  const int m = lane & 31;
  const int hh = lane >> 5;

  const int blk = blockIdx.x;          // 448 total
  const int xcd = blk & 7;
  const int r = blk >> 3;              // 0..55
  const int i4 = r / 14;               // 0..3
  const int rr = r - i4 * 14;          // 0..13
  const int bimg = xcd * 4 + i4;       // image on one XCD (L2 affinity)
  const int og = rr >> 1;              // 0..6  -> oh0 = 4*og
  const int cih = rr & 1;
  const int cic = cih * 4 + wave;      // this wave's 32-ci chunk

  const char* xb = (const char*)xt;
  const char* wb = (const char*)wt;

  // Row base at h = 8*og; row h adds h*32768.
  // In-row lane base: cic*4096 + hh*1024 + m*16; frag: p*2048 + (kw&1)*512
  // + (kw>>1)*16 (identical layout to r-1, correctness-proven).
  const char* base = xb + ((size_t)(bimg * 64 + 8 * og) * 32768 +
                           cic * 4096 + hh * 1024 + m * 16);
  const int boff = cic * 2048 + hh * 512 + m * 16;

#define ALOADR(H, KW, P)                                                 \
  (*(const f16x8*)(base + (size_t)(H) * 32768 + (P) * 2048 +             \
                   ((KW) & 1) * 512 + ((KW) >> 1) * 16))
#define BLOADK(KK, S) \
  (*(const f16x8*)(wb + (size_t)(KK) * 16384 + (S) * 1024 + boff))

  f32x16 acc0, acc1, acc2, acc3;
#pragma unroll
  for (int i = 0; i < 16; ++i) {
    acc0[i] = 0.f; acc1[i] = 0.f; acc2[i] = 0.f; acc3[i] = 0.f;
  }

#pragma unroll
  for (int kw = 0; kw < 9; ++kw) {
#pragma unroll
    for (int par = 0; par < 2; ++par) {
      const int nk = par ? 4 : 5;  // kh = par, par+2, ..., <9
      // Whole-chain B prefetch (deep, independent loads; <=10 frags = 40 VGPR)
      f16x8 bb0[5], bb1[5];
#pragma unroll
      for (int i = 0; i < 5; ++i) {
        if (i < nk) {
          bb0[i] = BLOADK((par + 2 * i) * 9 + kw, 0);
          bb1[i] = BLOADK((par + 2 * i) * 9 + kw, 1);
        }
      }
      // A shift register: rows h = 8og + par + 2t, t = 0..3
      f16x8 a00 = ALOADR(par + 0, kw, 0), a01 = ALOADR(par + 0, kw, 1);
      f16x8 a10 = ALOADR(par + 2, kw, 0), a11 = ALOADR(par + 2, kw, 1);
      f16x8 a20 = ALOADR(par + 4, kw, 0), a21 = ALOADR(par + 4, kw, 1);
      f16x8 a30 = ALOADR(par + 6, kw, 0), a31 = ALOADR(par + 6, kw, 1);
#pragma unroll
      for (int i = 0; i < nk; ++i) {
        f16x8 n0, n1;
        if (i + 1 < nk) {  // prefetch next top row before the MFMAs
          n0 = ALOADR(par + 2 * i + 8, kw, 0);
          n1 = ALOADR(par + 2 * i + 8, kw, 1);
        }
        acc0 = MFMA(a00, bb0[i], acc0); acc0 = MFMA(a01, bb1[i], acc0);
        acc1 = MFMA(a10, bb0[i], acc1); acc1 = MFMA(a11, bb1[i], acc1);
        acc2 = MFMA(a20, bb0[i], acc2); acc2 = MFMA(a21, bb1[i], acc2);
        acc3 = MFMA(a30, bb0[i], acc3); acc3 = MFMA(a31, bb1[i], acc3);
        if (i + 1 < nk) {  // shift (free after unroll: pure renaming)
          a00 = a10; a01 = a11;
          a10 = a20; a11 = a21;
          a20 = a30; a21 = a31;
          a30 = n0;  a31 = n1;
        }
      }
    }
  }
#undef ALOADR
#undef BLOADK

  // 4-wave reduction, four rounds (tile t -> oh = 4*og + t).
  const int mm = tid >> 3;        // 0..31 (ow)
  const int c0 = (tid & 7) * 4;   // 0..28
#define REDUCE_ROUND(ACC, T)                                                   \
  {                                                                            \
    __syncthreads();                                                           \
    _Pragma("unroll") for (int rI = 0; rI < 16; ++rI) {                        \
      const int row = (rI & 3) + 8 * (rI >> 2) + 4 * hh;                       \
      red[(wave * 32 + row) * 33 + m] = (ACC)[rI];                             \
    }                                                                          \
    __syncthreads();                                                           \
    if (mm < 28) {                                                             \
      float s0 = 0.f, s1 = 0.f, s2 = 0.f, s3 = 0.f;                            \
      _Pragma("unroll") for (int w = 0; w < 4; ++w) {                          \
        const float* rp = red + (w * 32 + mm) * 33 + c0;                       \
        s0 += rp[0]; s1 += rp[1]; s2 += rp[2]; s3 += rp[3];                    \
      }                                                                        \
      const f32x4 o4 = {s0, s1, s2, s3};                                       \
      const int p = bimg * 784 + (4 * og + (T)) * 28 + mm;                     \
      *(f32x4*)&convp[(size_t)cih * 802816 + (size_t)p * 32 + c0] = o4;        \
    }                                                                          \
  }
  REDUCE_ROUND(acc0, 0)
  REDUCE_ROUND(acc1, 1)
  REDUCE_ROUND(acc2, 2)
  REDUCE_ROUND(acc3, 3)
#undef REDUCE_ROUND
}

// ---------------------------------------------------------------------------
// Kernel 4: epilogue. v = sum(2 partials)+bias; sq=8v^2;
// scale = sq/((1+sq)*sqrt(sq+1e-8)); y=v*scale broadcast to 8 t-slots.
// (unchanged)
// ---------------------------------------------------------------------------
__global__ __launch_bounds__(256) void epilogue(const float* __restrict__ convp,
                                                const float* __restrict__ bias,
                                                float* __restrict__ out) {
  const int gi = blockIdx.x * 256 + threadIdx.x;  // 100352 total, exact grid
  const int base = gi * 8;
  const int p = gi >> 2;
  const int co0 = (gi & 3) * 8;
  const int bi = p / 784;
  const int pix = p - bi * 784;
  f32x4 v0 = {0.f, 0.f, 0.f, 0.f}, v1 = {0.f, 0.f, 0.f, 0.f};
#pragma unroll
  for (int qq = 0; qq < 2; ++qq) {
    v0 += *(const f32x4*)&convp[(size_t)qq * 802816 + base];
    v1 += *(const f32x4*)&convp[(size_t)qq * 802816 + base + 4];
  }
  float vb[8];
#pragma unroll
  for (int jj = 0; jj < 4; ++jj) {
    vb[jj] = v0[jj] + bias[co0 + jj];
    vb[4 + jj] = v1[jj] + bias[co0 + 4 + jj];
  }
  float* ob = out + (size_t)bi * 200704 + pix * 8;
#pragma unroll
  for (int jj = 0; jj < 8; ++jj) {
    const float vv = vb[jj];
    const float sq = 8.f * vv * vv;
    const float scale = sq / ((1.f + sq) * sqrtf(sq + 1e-8f));
    const float y = vv * scale;
    const f32x4 qv = {y, y, y, y};
    float* o = ob + (size_t)(co0 + jj) * 6272;
    *(f32x4*)o = qv;
    *(f32x4*)(o + 4) = qv;
  }
}

// ---------------------------------------------------------------------------
extern "C" void kernel_launch(void* const* d_in, const int* in_sizes, int n_in,
                              void* d_out, int out_size, void* d_ws,
                              size_t ws_size, hipStream_t stream) {
  const float* x = (const float*)d_in[0];     // [32,256,64,64]
  const float* W = (const float*)d_in[1];     // [32,256,9,9]
  const float* bias = (const float*)d_in[2];  // [32]
  float* out = (float*)d_out;                 // 6422528 f32

  char* ws = (char*)d_ws;
  f16* xt = (f16*)ws;                                // 67,108,864 B
  f16* wt = (f16*)(ws + 67108864);                   //  1,327,104 B
  float* convp = (float*)(ws + 67108864 + 1327104);  //  6,422,528 B (2 halves)

  nchw_to_nhwc_f16<<<dim3(2048), dim3(256), 0, stream>>>(x, xt);
  pack_w<<<dim3(64), dim3(256), 0, stream>>>(W, wt);
  conv_direct<<<dim3(448), dim3(256), 0, stream>>>(xt, wt, convp);
  epilogue<<<dim3(392), dim3(256), 0, stream>>>(convp, bias, out);
}

// Round 3
// 285.535 us; speedup vs baseline: 1.3200x; 1.0948x over previous
//
#include <hip/hip_runtime.h>
#include <hip/hip_bf16.h>
#include <stdint.h>

typedef _Float16 f16;
typedef _Float16 f16x8 __attribute__((ext_vector_type(8)));
typedef float f32x16 __attribute__((ext_vector_type(16)));
typedef float f32x4 __attribute__((ext_vector_type(4)));
typedef uint32_t u32x4 __attribute__((ext_vector_type(4)));
typedef uint32_t u32x2 __attribute__((ext_vector_type(2)));

#define MFMA(A, B, C) __builtin_amdgcn_mfma_f32_32x32x16_f16((A), (B), (C), 0, 0, 0)

// ---------------------------------------------------------------------------
// Kernel 1: x NCHW f32 [32,256,64,64] -> xt2 f16, MFMA-native layout:
//   16B unit U = ((((b*64+h)*8 + c32)*4 + g)*2 + (w&1))*32 + (w>>1)
//   (c = c32*32 + g*8 + e). A-fragment loads become contiguous 512B runs.
// (unchanged, correctness-proven)
// ---------------------------------------------------------------------------
__global__ __launch_bounds__(256) void nchw_to_nhwc_f16(
    const float* __restrict__ x, f16* __restrict__ xt) {
  __shared__ __align__(16) uint32_t tile[64 * 128];  // 32768 B
  const int bh = blockIdx.x;  // b*64 + h
  const int t = threadIdx.x;
  const float* src = x + (size_t)(bh >> 6) * (256 * 4096) + (bh & 63) * 64;

  const int w4 = t & 15;            // float4 index along w
  const int cq = t >> 4;            // c-quad 0..15
  const int xorv = 4 * (w4 & 7);    // = 4*((w>>2)&7) since w = w4*4+jw
#pragma unroll
  for (int it = 0; it < 4; ++it) {
    const int c0 = it * 64 + cq * 4;
    float4 v0 = *(const float4*)(src + (size_t)(c0 + 0) * 4096 + w4 * 4);
    float4 v1 = *(const float4*)(src + (size_t)(c0 + 1) * 4096 + w4 * 4);
    float4 v2 = *(const float4*)(src + (size_t)(c0 + 2) * 4096 + w4 * 4);
    float4 v3 = *(const float4*)(src + (size_t)(c0 + 3) * 4096 + w4 * 4);
    const float* p0 = (const float*)&v0;
    const float* p1 = (const float*)&v1;
    const float* p2 = (const float*)&v2;
    const float* p3 = (const float*)&v3;
    const int u = it * 32 + cq * 2;  // even word index (c-pair)
#pragma unroll
    for (int jw = 0; jw < 4; ++jw) {
      f16 h0 = (f16)p0[jw], h1 = (f16)p1[jw], h2 = (f16)p2[jw], h3 = (f16)p3[jw];
      uint32_t lo = (uint32_t)__builtin_bit_cast(uint16_t, h0) |
                    ((uint32_t)__builtin_bit_cast(uint16_t, h1) << 16);
      uint32_t hi = (uint32_t)__builtin_bit_cast(uint16_t, h2) |
                    ((uint32_t)__builtin_bit_cast(uint16_t, h3) << 16);
      u32x2 pk = {lo, hi};
      const int w = w4 * 4 + jw;
      *(u32x2*)&tile[w * 128 + (u ^ xorv)] = pk;
    }
  }
  __syncthreads();
  f16* dstb = xt + (size_t)bh * 16384;
#pragma unroll
  for (int it = 0; it < 8; ++it) {
    const int n = it * 256 + t;       // local 16B-unit index, 0..2047
    const int w2 = n & 31;
    const int par = (n >> 5) & 1;
    const int g8 = n >> 6;            // c-octet 0..31
    const int w = par + 2 * w2;
    const u32x4 v = *(const u32x4*)&tile[w * 128 + ((g8 * 4) ^ (4 * ((w >> 2) & 7)))];
    *(u32x4*)(dstb + n * 8) = v;
  }
}

// ---------------------------------------------------------------------------
// Kernel 2: W [32co][256ci][9][9] f32 -> wt2 f16:
//   byte = (((kk*8 + cic)*4 + sg)*32 + co)*16 + e*2,  ci = cic*32 + s*16+hh*8+e,
//   sg = s*2+hh. B-fragment loads become two contiguous 512B runs.
// (unchanged)
// ---------------------------------------------------------------------------
__global__ __launch_bounds__(256) void pack_w(const float* __restrict__ W,
                                              f16* __restrict__ wt) {
  __shared__ float lds[10368];  // [128 ci][81 kk]
  const int t = threadIdx.x;
  const int co = blockIdx.x >> 1;
  const int cih = blockIdx.x & 1;
  const float* src = W + (size_t)(co * 256 + cih * 128) * 81;
  for (int i = t; i < 10368; i += 256) lds[i] = src[i];
  __syncthreads();
  for (int j = t; j < 1296; j += 256) {
    const int kk = j >> 4;
    const int t16 = j & 15;
    const int cicl = t16 >> 2;       // cic within half, 0..3
    const int sg = t16 & 3;          // s*2 + hh
    const int cin = ((sg >> 1) & 1) * 16 + (sg & 1) * 8;  // ci offset in 32
    f16 tmp[8];
#pragma unroll
    for (int e = 0; e < 8; ++e)
      tmp[e] = (f16)lds[(cicl * 32 + cin + e) * 81 + kk];
    const int cic = cih * 4 + cicl;
    *(f16x8*)&wt[(size_t)(((kk * 8 + cic) * 4 + sg) * 32 + co) * 8] = *(f16x8*)tmp;
  }
}

// ---------------------------------------------------------------------------
// Kernel 3: direct conv — waves = M-tiles, block-shared B via LDS.
// r3 redesign from r1/r2 post-mortems:
//  * Block = (img, og, cic): ONE 32-ci chunk per block; 4 waves each own one
//    oh-pair (T0/T1 like baseline, A shared in-reg across the pair). All
//    waves walk kh=j in LOCKSTEP -> identical B fragments -> B staged once
//    per slab in LDS (18KB, global_load_lds w=16), shared by 4 waves.
//    B L2 traffic /4; A keeps the proven kw-inner L1 pattern untouched.
//  * Barrier cadence: ONE per slab (144 MFMAs/block between barriers) —
//    r0's per-step drain (4 MFMAs/barrier) is what collapsed; this is 36x
//    coarser, stage latency fully hidden under prior slab's compute.
//  * 4-deep LDS ring (72KB): slab j reads stage[j] (T0) + stage[j-2] (T1)
//    while stage[j+1] fills. 2 blocks/CU by LDS.
//  * No cross-wave reduction: 8 convp partials, summed in epilogue.
// Grid 1024 = 8 xcd x 4 img x 4 og x 8 cic. oh padded 28->32: ohp>=14 waves
// idle through barriers (no OOB reads, no junk MFMAs).
// ---------------------------------------------------------------------------
__global__ __launch_bounds__(256, 2) void conv_direct(
    const f16* __restrict__ xt, const f16* __restrict__ wt,
    float* __restrict__ convp) {
  __shared__ __align__(16) char stg[4 * 18432];  // 73728 B ring
  const int tid = threadIdx.x;
  const int lane = tid & 63;
  const int wave = tid >> 6;
  const int m = lane & 31;
  const int hh = lane >> 5;

  const int blk = blockIdx.x;          // 1024 total
  const int xcd = blk & 7;
  const int r = blk >> 3;              // 0..127
  const int i4 = r >> 5;               // 0..3
  const int rr = r & 31;
  const int og = rr >> 3;              // 0..3
  const int cic = rr & 7;              // 0..7 (this block's 32-ci chunk)
  const int bimg = xcd * 4 + i4;       // image on one XCD (L2 affinity)
  const int ohp = og * 4 + wave;       // 0..15; this wave's oh-pair
  const bool active = (ohp < 14);      // oh 28..31 is padding

  const char* xb = (const char*)xt;
  const char* wb = (const char*)wt;

  // A lane base for slab j=0: byte = (bimg*64 + 4*ohp)*32768 + cic*4096
  //                                  + hh*1024 + m*16 ; per slab += 32768.
  // Frag: p*2048 + (kw&1)*512 + (kw>>1)*16  (baseline-proven layout).
  const char* ab = xb + ((size_t)(bimg * 64 + 4 * ohp) * 32768 +
                         cic * 4096 + hh * 1024 + m * 16);
  const size_t cic2048 = (size_t)cic * 2048;
  const int fragoff = hh * 512 + m * 16;  // in-chunk LDS read offset

#define GLDS(G, L)                                                            \
  __builtin_amdgcn_global_load_lds(                                           \
      (const __attribute__((address_space(1))) void*)(G),                     \
      (__attribute__((address_space(3))) void*)(L), 16, 0, 0)

#define ALOAD(AB, KW, P) \
  (*(const f16x8*)((AB) + (P) * 2048 + ((KW) & 1) * 512 + ((KW) >> 1) * 16))
#define LDSF(P) (*(const f16x8*)(P))

  // Stage slab JN's 9 kk-chunks (kk = JN*9..JN*9+8), this cic slice:
  // 9 x 2KB = 18432 B -> ring slot JN&3. Lane-linear LDS dest (HW req).
#define STAGE(JN)                                                             \
  {                                                                           \
    const int kkb = (JN) * 9;                                                 \
    char* db = stg + ((JN) & 3) * 18432;                                      \
    _Pragma("unroll") for (int i = 0; i < 4; ++i) {                           \
      const int u = tid + 256 * i;                                            \
      GLDS(wb + (size_t)(kkb + (u >> 7)) * 16384 + cic2048 + (u & 127) * 16,  \
           db + u * 16);                                                      \
    }                                                                         \
    if (tid < 128) {                                                          \
      GLDS(wb + (size_t)(kkb + 8) * 16384 + cic2048 + tid * 16,               \
           db + 16384 + tid * 16);                                            \
    }                                                                         \
  }

  f32x16 acc0, acc1;
#pragma unroll
  for (int i = 0; i < 16; ++i) { acc0[i] = 0.f; acc1[i] = 0.f; }

  STAGE(0)  // prologue: stage slab 0 (latency paid once)

  for (int j = 0; j < 11; ++j) {
    __syncthreads();            // stage[j] ready; prior slab's LDS reads done
    if (j < 8) STAGE(j + 1)     // fill next slot under this slab's compute
    if (active) {
      const char* s0 = stg + (j & 3) * 18432 + fragoff;        // T0: kh=j
      const char* s1 = stg + ((j + 2) & 3) * 18432 + fragoff;  // T1: kh=j-2
      if (j >= 2 && j <= 8) {
#pragma unroll
        for (int kw = 0; kw < 9; ++kw) {
          const f16x8 a0 = ALOAD(ab, kw, 0), a1 = ALOAD(ab, kw, 1);
          acc0 = MFMA(a0, LDSF(s0 + kw * 2048), acc0);
          acc0 = MFMA(a1, LDSF(s0 + kw * 2048 + 1024), acc0);
          acc1 = MFMA(a0, LDSF(s1 + kw * 2048), acc1);
          acc1 = MFMA(a1, LDSF(s1 + kw * 2048 + 1024), acc1);
        }
      } else if (j < 2) {  // T0 only
#pragma unroll
        for (int kw = 0; kw < 9; ++kw) {
          const f16x8 a0 = ALOAD(ab, kw, 0), a1 = ALOAD(ab, kw, 1);
          acc0 = MFMA(a0, LDSF(s0 + kw * 2048), acc0);
          acc0 = MFMA(a1, LDSF(s0 + kw * 2048 + 1024), acc0);
        }
      } else {             // j > 8: T1 only
#pragma unroll
        for (int kw = 0; kw < 9; ++kw) {
          const f16x8 a0 = ALOAD(ab, kw, 0), a1 = ALOAD(ab, kw, 1);
          acc1 = MFMA(a0, LDSF(s1 + kw * 2048), acc1);
          acc1 = MFMA(a1, LDSF(s1 + kw * 2048 + 1024), acc1);
        }
      }
    }
    ab += 32768;
  }
#undef STAGE
#undef ALOAD
#undef LDSF
#undef GLDS

  // Direct store (no cross-wave reduction): acc reg r, lane (m,hh) holds
  // D[ow = (r&3)+8*(r>>2)+4*hh][co = m]. Half-wave 128B segments, coalesced.
  if (active) {
#pragma unroll
    for (int tile = 0; tile < 2; ++tile) {
      const int oh = 2 * ohp + tile;
      float* cp = convp + (size_t)cic * 802816 +
                  ((size_t)bimg * 784 + oh * 28) * 32 + m;
      const f32x16& a = tile ? acc1 : acc0;
#pragma unroll
      for (int rI = 0; rI < 16; ++rI) {
        const int ow = (rI & 3) + 8 * (rI >> 2) + 4 * hh;
        if (ow < 28) cp[ow * 32] = a[rI];
      }
    }
  }
}

// ---------------------------------------------------------------------------
// Kernel 4: epilogue. v = sum(8 partials)+bias; sq=8v^2;
// scale = sq/((1+sq)*sqrt(sq+1e-8)); y=v*scale broadcast to 8 t-slots.
// ---------------------------------------------------------------------------
__global__ __launch_bounds__(256) void epilogue(const float* __restrict__ convp,
                                                const float* __restrict__ bias,
                                                float* __restrict__ out) {
  const int gi = blockIdx.x * 256 + threadIdx.x;  // 100352 total, exact grid
  const int base = gi * 8;
  const int p = gi >> 2;
  const int co0 = (gi & 3) * 8;
  const int bi = p / 784;
  const int pix = p - bi * 784;
  f32x4 v0 = {0.f, 0.f, 0.f, 0.f}, v1 = {0.f, 0.f, 0.f, 0.f};
#pragma unroll
  for (int qq = 0; qq < 8; ++qq) {
    v0 += *(const f32x4*)&convp[(size_t)qq * 802816 + base];
    v1 += *(const f32x4*)&convp[(size_t)qq * 802816 + base + 4];
  }
  float vb[8];
#pragma unroll
  for (int jj = 0; jj < 4; ++jj) {
    vb[jj] = v0[jj] + bias[co0 + jj];
    vb[4 + jj] = v1[jj] + bias[co0 + 4 + jj];
  }
  float* ob = out + (size_t)bi * 200704 + pix * 8;
#pragma unroll
  for (int jj = 0; jj < 8; ++jj) {
    const float vv = vb[jj];
    const float sq = 8.f * vv * vv;
    const float scale = sq / ((1.f + sq) * sqrtf(sq + 1e-8f));
    const float y = vv * scale;
    const f32x4 qv = {y, y, y, y};
    float* o = ob + (size_t)(co0 + jj) * 6272;
    *(f32x4*)o = qv;
    *(f32x4*)(o + 4) = qv;
  }
}

// ---------------------------------------------------------------------------
extern "C" void kernel_launch(void* const* d_in, const int* in_sizes, int n_in,
                              void* d_out, int out_size, void* d_ws,
                              size_t ws_size, hipStream_t stream) {
  const float* x = (const float*)d_in[0];     // [32,256,64,64]
  const float* W = (const float*)d_in[1];     // [32,256,9,9]
  const float* bias = (const float*)d_in[2];  // [32]
  float* out = (float*)d_out;                 // 6422528 f32

  char* ws = (char*)d_ws;
  f16* xt = (f16*)ws;                                // 67,108,864 B
  f16* wt = (f16*)(ws + 67108864);                   //  1,327,104 B
  float* convp = (float*)(ws + 67108864 + 1327104);  // 25,690,112 B (8 parts)

  nchw_to_nhwc_f16<<<dim3(2048), dim3(256), 0, stream>>>(x, xt);
  pack_w<<<dim3(64), dim3(256), 0, stream>>>(W, wt);
  conv_direct<<<dim3(1024), dim3(256), 0, stream>>>(xt, wt, convp);
  epilogue<<<dim3(392), dim3(256), 0, stream>>>(convp, bias, out);
}